// Round 4
// baseline (985.161 us; speedup 1.0000x reference)
//
#include <hip/hip_runtime.h>
#include <math.h>

#define BB 4096
#define LL 200
#define EE 128
#define FF 64
#define NTHREADS 512   // 8 waves; each wave owns 16 output columns (one N-tile)

// LDS row pitches (bf16 elems). pitch_bytes = 16*odd -> A-operand ds_read_b128
// 16B-column index = (9m+q) mod 8, uniform -> conflict-free.
#define PITCH_F  72     // features K=64  (+8 pad), 144 B = 16*9
#define PITCH_FX 136    // fx       K=128 (+8 pad), 272 B = 16*17
#define PITCH_X3 264    // items|comp K=256 (+8 pad), 528 B = 16*33

typedef __attribute__((ext_vector_type(4))) float  floatx4;
typedef __attribute__((ext_vector_type(8))) short  shortx8;

#define MFMA16(a, b, c) __builtin_amdgcn_mfma_f32_16x16x32_bf16((a), (b), (c), 0, 0, 0)

__device__ __forceinline__ unsigned short f2bf(float f) {
    union { float f; unsigned u; } c; c.f = f;
    return (unsigned short)((c.u + 0x7fffu + ((c.u >> 16) & 1u)) >> 16);
}

// load 8 consecutive fp32, round to bf16, return MFMA B-fragment
__device__ __forceinline__ shortx8 load_bfrag(const float* p) {
    float4 v0 = ((const float4*)p)[0];
    float4 v1 = ((const float4*)p)[1];
    shortx8 r;
    r[0] = (short)f2bf(v0.x); r[1] = (short)f2bf(v0.y);
    r[2] = (short)f2bf(v0.z); r[3] = (short)f2bf(v0.w);
    r[4] = (short)f2bf(v1.x); r[5] = (short)f2bf(v1.y);
    r[6] = (short)f2bf(v1.z); r[7] = (short)f2bf(v1.w);
    return r;
}

__device__ __forceinline__ float waveMax(float v) {
    #pragma unroll
    for (int off = 32; off > 0; off >>= 1)
        v = fmaxf(v, __shfl_xor(v, off, 64));
    return v;
}
__device__ __forceinline__ float waveSum(float v) {
    #pragma unroll
    for (int off = 32; off > 0; off >>= 1)
        v += __shfl_xor(v, off, 64);
    return v;
}

// waves_per_eu(2,4): cap occupancy target at 4 waves/EU (LDS limits us to 4
// anyway at 72.7KB -> 2 blocks/CU) so the allocator gives us >=128 VGPRs and
// the persistent B fragments (56 VGPRs) don't spill to scratch.
// R3 evidence: __launch_bounds__(512,4) alone -> compiler chose 64 VGPRs,
// 117 MB of scratch WRITE_SIZE.
__global__ __attribute__((amdgpu_flat_work_group_size(512, 512), amdgpu_waves_per_eu(2, 4)))
void usernet_mfma(const int* __restrict__ user_ids,
                  const int* __restrict__ item_ids,
                  const float* __restrict__ features,
                  const float* __restrict__ user_emb,
                  const float* __restrict__ item_emb,
                  const float* __restrict__ feat_w1,
                  const float* __restrict__ feat_b1,
                  const float* __restrict__ feat_w2,
                  const float* __restrict__ feat_b2,
                  const float* __restrict__ w1,
                  const float* __restrict__ b1,
                  const float* __restrict__ w2,
                  const float* __restrict__ b2,
                  float* __restrict__ out)
{
    __shared__ __align__(16) unsigned short s_feat[64 * PITCH_F];   //  9216 B
    __shared__ __align__(16) unsigned short s_fx  [64 * PITCH_FX];  // 17408 B
    __shared__ __align__(16) unsigned short s_x3  [64 * PITCH_X3];  // 33792 B
    __shared__ float s_user[EE];
    __shared__ float s_bias1[EE];   // u1 + feat_b1
    __shared__ float s_bias2[EE];   // feat_b2
    __shared__ float s_bias3[EE];   // u3 + b1
    __shared__ float s_w2[EE];
    __shared__ float s_lp[8][208];  // per-wave logit partials (6656 B)
    __shared__ float s_attn[208];
    __shared__ float s_red[12];
    __shared__ float s_part[4][EE];

    const int b    = blockIdx.x;
    const int tid  = threadIdx.x;
    const int lane = tid & 63;
    const int wv   = tid >> 6;         // wave id 0..7: owns output cols [16*wv, 16*wv+16)
    const int m    = lane & 15;
    const int q    = lane >> 4;
    const int n0   = wv * 16 + m;      // owned output col for this lane

    // ---- persistent B fragments (56 VGPRs/wave; user cols folded out) ----
    shortx8 B1[2];   // feat_w1 features part, K=64
    shortx8 B2[4];   // feat_w2, K=128
    shortx8 B3[8];   // w1 item|comp part, K=256
    #pragma unroll
    for (int ks = 0; ks < 2; ++ks)
        B1[ks] = load_bfrag(feat_w1 + (size_t)n0 * (EE + FF) + EE + ks * 32 + q * 8);
    #pragma unroll
    for (int ks = 0; ks < 4; ++ks)
        B2[ks] = load_bfrag(feat_w2 + (size_t)n0 * EE + ks * 32 + q * 8);
    #pragma unroll
    for (int ks = 0; ks < 8; ++ks)
        B3[ks] = load_bfrag(w1 + (size_t)n0 * (3 * EE) + EE + ks * 32 + q * 8);

    // ---- user row + small vectors ----
    if (tid < 32) {
        const int uid = user_ids[b];
        ((float4*)s_user)[tid] = ((const float4*)(user_emb + (size_t)uid * EE))[tid];
    }
    if (tid >= 64 && tid < 64 + EE) {
        s_bias2[tid - 64] = feat_b2[tid - 64];
        s_w2[tid - 64]    = w2[tid - 64];
    }
    __syncthreads();

    // ---- fp32 user folds: bias1 = W1a@user + feat_b1 ; bias3 = W3a@user + b1 ----
    if (tid < 256) {
        const int e    = tid & (EE - 1);
        const int half = tid >> 7;
        const float* wrow = half ? (w1 + (size_t)e * (3 * EE))
                                 : (feat_w1 + (size_t)e * (EE + FF));
        float acc = 0.f;
        #pragma unroll 8
        for (int k = 0; k < EE; ++k) acc += wrow[k] * s_user[k];
        if (half == 0) s_bias1[e] = acc + feat_b1[e];
        else           s_bias3[e] = acc + b1[e];
    }
    __syncthreads();

    const float bias1_0 = s_bias1[n0];
    const float bias2_0 = s_bias2[n0];
    const float bias3_0 = s_bias3[n0];
    const float w2_0    = s_w2[n0];

    // ---- chunk loop: 13 M-tiles of 16 rows, in chunks of (4,4,4,1) tiles ----
    for (int ch = 0; ch < 4; ++ch) {
        const int row0 = ch * 64;
        const int ntl  = (ch < 3) ? 4 : 1;
        const int rows = ntl * 16;

        // stage features -> bf16 LDS [row][k] (pad rows = 0)
        for (int idx = tid; idx < rows * 16; idx += NTHREADS) {
            const int r = idx >> 4, c4 = idx & 15;
            const int l = row0 + r;
            float4 v = make_float4(0.f, 0.f, 0.f, 0.f);
            if (l < LL) v = ((const float4*)features)[((size_t)b * LL + l) * 16 + c4];
            ushort4 o; o.x = f2bf(v.x); o.y = f2bf(v.y); o.z = f2bf(v.z); o.w = f2bf(v.w);
            *(ushort4*)&s_feat[r * PITCH_F + c4 * 4] = o;
        }
        // stage gathered item rows -> bf16 LDS x3[row][0..127]
        for (int idx = tid; idx < rows * 32; idx += NTHREADS) {
            const int r = idx >> 5, c4 = idx & 31;
            const int l = row0 + r;
            float4 v = make_float4(0.f, 0.f, 0.f, 0.f);
            if (l < LL) {
                const int id = item_ids[(size_t)b * LL + l];
                v = ((const float4*)item_emb)[(size_t)id * 32 + c4];
            }
            ushort4 o; o.x = f2bf(v.x); o.y = f2bf(v.y); o.z = f2bf(v.z); o.w = f2bf(v.w);
            *(ushort4*)&s_x3[r * PITCH_X3 + c4 * 4] = o;
        }
        __syncthreads();

        // layer 1: fx = relu(feat @ W1f^T + bias1)
        for (int mt = 0; mt < ntl; ++mt) {
            floatx4 a0 = {0.f, 0.f, 0.f, 0.f};
            const unsigned short* ap = s_feat + (mt * 16 + m) * PITCH_F + q * 8;
            #pragma unroll
            for (int ks = 0; ks < 2; ++ks) {
                shortx8 af = *(const shortx8*)(ap + ks * 32);
                a0 = MFMA16(af, B1[ks], a0);
            }
            #pragma unroll
            for (int r = 0; r < 4; ++r) {
                const int row = mt * 16 + q * 4 + r;
                float v0 = a0[r] + bias1_0; v0 = v0 > 0.f ? v0 : 0.f;
                s_fx[row * PITCH_FX + n0] = f2bf(v0);
            }
        }
        __syncthreads();

        // layer 2: comp = relu(fx @ W2^T + bias2) -> x3 cols 128..255
        for (int mt = 0; mt < ntl; ++mt) {
            floatx4 a0 = {0.f, 0.f, 0.f, 0.f};
            const unsigned short* ap = s_fx + (mt * 16 + m) * PITCH_FX + q * 8;
            #pragma unroll
            for (int ks = 0; ks < 4; ++ks) {
                shortx8 af = *(const shortx8*)(ap + ks * 32);
                a0 = MFMA16(af, B2[ks], a0);
            }
            #pragma unroll
            for (int r = 0; r < 4; ++r) {
                const int row = mt * 16 + q * 4 + r;
                float v0 = a0[r] + bias2_0; v0 = v0 > 0.f ? v0 : 0.f;
                s_x3[row * PITCH_X3 + EE + n0] = f2bf(v0);
            }
        }
        __syncthreads();

        // layer 3: h = relu([items|comp] @ W3'^T + bias3); logit partial = w2[n]*h
        for (int mt = 0; mt < ntl; ++mt) {
            floatx4 a0 = {0.f, 0.f, 0.f, 0.f};
            const unsigned short* ap = s_x3 + (mt * 16 + m) * PITCH_X3 + q * 8;
            #pragma unroll
            for (int ks = 0; ks < 8; ++ks) {
                shortx8 af = *(const shortx8*)(ap + ks * 32);
                a0 = MFMA16(af, B3[ks], a0);
            }
            #pragma unroll
            for (int r = 0; r < 4; ++r) {
                float v0 = a0[r] + bias3_0; v0 = v0 > 0.f ? v0 : 0.f;
                float p = v0 * w2_0;
                p += __shfl_xor(p, 1, 64);   // reduce over the 16-lane n dim
                p += __shfl_xor(p, 2, 64);
                p += __shfl_xor(p, 4, 64);
                p += __shfl_xor(p, 8, 64);
                if (m == 0) s_lp[wv][row0 + mt * 16 + q * 4 + r] = p;
            }
        }
        __syncthreads();
    }

    // ---- softmax over L=200 ----
    const int wid = tid >> 6;
    float lv = -INFINITY;
    if (tid < LL) {
        lv = b2[0];
        #pragma unroll
        for (int w = 0; w < 8; ++w) lv += s_lp[w][tid];
    }
    {
        float mx = waveMax(lv);
        if ((tid & 63) == 0) s_red[wid] = mx;
        __syncthreads();
        if (tid == 0) {
            float g = s_red[0];
            #pragma unroll
            for (int w = 1; w < 8; ++w) g = fmaxf(g, s_red[w]);
            s_red[8] = g;
        }
        __syncthreads();
    }
    const float gmax = s_red[8];
    __syncthreads();
    float ex = (tid < LL) ? __expf(lv - gmax) : 0.f;
    {
        float s = waveSum(ex);
        if ((tid & 63) == 0) s_red[wid] = s;
        __syncthreads();
        if (tid == 0) {
            float g = 0.f;
            #pragma unroll
            for (int w = 0; w < 8; ++w) g += s_red[w];
            s_red[8] = g;
        }
        __syncthreads();
    }
    const float inv = 1.f / s_red[8];
    if (tid < LL) s_attn[tid] = ex * inv;
    __syncthreads();

    // ---- out[b] = user + sum_l attn[l] * item_emb[item_ids[b,l]]  (fp32) ----
    {
        const int e = tid & (EE - 1);
        const int g = tid >> 7;            // 0..3, each covers 50 l's
        float acc = 0.f;
        const int lstart = g * (LL / 4);
        for (int l = lstart; l < lstart + LL / 4; ++l) {
            const float a  = s_attn[l];
            const int  id  = item_ids[(size_t)b * LL + l];
            acc += a * item_emb[(size_t)id * EE + e];
        }
        s_part[g][e] = acc;
        __syncthreads();
        if (tid < EE)
            out[(size_t)b * EE + tid] = s_user[tid] + s_part[0][tid] + s_part[1][tid]
                                      + s_part[2][tid] + s_part[3][tid];
    }
}

extern "C" void kernel_launch(void* const* d_in, const int* in_sizes, int n_in,
                              void* d_out, int out_size, void* d_ws, size_t ws_size,
                              hipStream_t stream) {
    const int*   user_ids = (const int*)  d_in[0];
    const int*   item_ids = (const int*)  d_in[1];
    const float* features = (const float*)d_in[2];
    const float* user_emb = (const float*)d_in[3];
    const float* item_emb = (const float*)d_in[4];
    const float* feat_w1  = (const float*)d_in[5];
    const float* feat_b1  = (const float*)d_in[6];
    const float* feat_w2  = (const float*)d_in[7];
    const float* feat_b2  = (const float*)d_in[8];
    const float* w1       = (const float*)d_in[9];
    const float* b1       = (const float*)d_in[10];
    const float* w2       = (const float*)d_in[11];
    const float* b2       = (const float*)d_in[12];
    float* out = (float*)d_out;

    usernet_mfma<<<BB, NTHREADS, 0, stream>>>(user_ids, item_ids, features,
                                              user_emb, item_emb,
                                              feat_w1, feat_b1, feat_w2, feat_b2,
                                              w1, b1, w2, b2, out);
}

// Round 5
// 928.147 us; speedup vs baseline: 1.0614x; 1.0614x over previous
//
#include <hip/hip_runtime.h>
#include <math.h>

#define BB 4096
#define LL 200
#define EE 128
#define FF 64
#define NTHREADS 512   // 8 waves = 4 N-groups (32 cols each) x 2 M-halves

// LDS row pitches (bf16 elems). pitch_bytes = 16*odd -> A-operand ds_read_b128
// 16B-column index = (odd*m+q) mod 8, uniform -> conflict-free.
#define PITCH_F  72     // features K=64  (+8 pad), 144 B = 16*9
#define PITCH_FX 136    // fx       K=128 (+8 pad), 272 B = 16*17
#define PITCH_X3 264    // items|comp K=256 (+8 pad), 528 B = 16*33

// bf16 weight table layout in d_ws (prepped by prep_weights each launch):
//   [0      .. 8192 )  feat_w1 feature part  [n=128][k=64]
//   [8192   .. 24576)  feat_w2               [n=128][k=128]
//   [24576  .. 57344)  w1 item|comp part     [n=128][k=256]
#define WS_W1 0
#define WS_W2 8192
#define WS_W3 24576
#define WS_TOTAL 57344

typedef __attribute__((ext_vector_type(4))) float  floatx4;
typedef __attribute__((ext_vector_type(8))) short  shortx8;

#define MFMA16(a, b, c) __builtin_amdgcn_mfma_f32_16x16x32_bf16((a), (b), (c), 0, 0, 0)

__device__ __forceinline__ unsigned short f2bf(float f) {
    union { float f; unsigned u; } c; c.f = f;
    return (unsigned short)((c.u + 0x7fffu + ((c.u >> 16) & 1u)) >> 16);
}

__device__ __forceinline__ float waveMax(float v) {
    #pragma unroll
    for (int off = 32; off > 0; off >>= 1)
        v = fmaxf(v, __shfl_xor(v, off, 64));
    return v;
}
__device__ __forceinline__ float waveSum(float v) {
    #pragma unroll
    for (int off = 32; off > 0; off >>= 1)
        v += __shfl_xor(v, off, 64);
    return v;
}

// One-time (per launch) fp32 -> bf16 weight repack into B-fragment-friendly rows.
__global__ __launch_bounds__(256)
void prep_weights(const float* __restrict__ feat_w1,
                  const float* __restrict__ feat_w2,
                  const float* __restrict__ w1,
                  unsigned short* __restrict__ wsw)
{
    int i = blockIdx.x * 256 + threadIdx.x;
    if (i >= WS_TOTAL) return;
    float v;
    if (i < WS_W2) {                       // feat_w1 feature cols
        int n = i >> 6, k = i & 63;
        v = feat_w1[n * (EE + FF) + EE + k];
    } else if (i < WS_W3) {                // feat_w2
        int j = i - WS_W2;
        int n = j >> 7, k = j & 127;
        v = feat_w2[n * EE + k];
    } else {                               // w1 item|comp cols
        int j = i - WS_W3;
        int n = j >> 8, k = j & 255;
        v = w1[n * (3 * EE) + EE + k];
    }
    wsw[i] = f2bf(v);
}

// R2-R4 lesson: persistent per-thread B-fragments (112 VGPRs) get spilled
// (R2/R3: WRITE_SIZE 117-207MB) or rematerialized with f2bf chains (R4: VGPR=72,
// latency-bound). Instead: B-frags are loaded per layer-phase from a prepped
// bf16 table (L2-hot, single dwordx4, no VALU), live range = one phase.
__global__ __launch_bounds__(NTHREADS, 2)
void usernet_mfma(const int* __restrict__ user_ids,
                  const int* __restrict__ item_ids,
                  const float* __restrict__ features,
                  const float* __restrict__ user_emb,
                  const float* __restrict__ item_emb,
                  const float* __restrict__ feat_w1,
                  const float* __restrict__ feat_b1,
                  const float* __restrict__ feat_b2,
                  const float* __restrict__ w1,
                  const float* __restrict__ b1,
                  const float* __restrict__ w2,
                  const float* __restrict__ b2,
                  const unsigned short* __restrict__ wsw,
                  float* __restrict__ out)
{
    __shared__ __align__(16) unsigned short s_feat[64 * PITCH_F];   //  9216 B
    __shared__ __align__(16) unsigned short s_fx  [64 * PITCH_FX];  // 17408 B
    __shared__ __align__(16) unsigned short s_x3  [64 * PITCH_X3];  // 33792 B
    __shared__ float s_user[EE];
    __shared__ float s_bias1[EE];   // u1 + feat_b1
    __shared__ float s_bias2[EE];   // feat_b2
    __shared__ float s_bias3[EE];   // u3 + b1
    __shared__ float s_w2[EE];
    __shared__ float s_lp[8][208];  // per-wave logit partials (6656 B)
    __shared__ float s_attn[208];
    __shared__ float s_red[12];
    __shared__ float s_part[4][EE];

    const int b    = blockIdx.x;
    const int tid  = threadIdx.x;
    const int lane = tid & 63;
    const int wv   = tid >> 6;
    const int nw   = wv & 3;           // N-group: cols [32*nw, 32*nw+32)
    const int mw   = wv >> 2;          // M-half within each 64-row chunk
    const int m    = lane & 15;
    const int q    = lane >> 4;
    const int c0   = nw * 32 + m;      // first owned col
    const int c1   = c0 + 16;          // second owned col

    // zero logit partials (waves only write their own M-half rows)
    for (int i = tid; i < 8 * 208; i += NTHREADS) ((float*)s_lp)[i] = 0.f;

    // ---- user row + small vectors ----
    if (tid < 32) {
        const int uid = user_ids[b];
        ((float4*)s_user)[tid] = ((const float4*)(user_emb + (size_t)uid * EE))[tid];
    }
    if (tid >= 64 && tid < 64 + EE) {
        s_bias2[tid - 64] = feat_b2[tid - 64];
        s_w2[tid - 64]    = w2[tid - 64];
    }
    __syncthreads();

    // ---- fp32 user folds: bias1 = W1a@user + feat_b1 ; bias3 = W3a@user + b1 ----
    if (tid < 256) {
        const int e    = tid & (EE - 1);
        const int half = tid >> 7;
        const float* wrow = half ? (w1 + (size_t)e * (3 * EE))
                                 : (feat_w1 + (size_t)e * (EE + FF));
        float acc = 0.f;
        #pragma unroll 8
        for (int k = 0; k < EE; ++k) acc += wrow[k] * s_user[k];
        if (half == 0) s_bias1[e] = acc + feat_b1[e];
        else           s_bias3[e] = acc + b1[e];
    }
    __syncthreads();

    const float bias1_0 = s_bias1[c0], bias1_1 = s_bias1[c1];
    const float bias2_0 = s_bias2[c0], bias2_1 = s_bias2[c1];
    const float bias3_0 = s_bias3[c0], bias3_1 = s_bias3[c1];
    const float w2_0    = s_w2[c0],    w2_1    = s_w2[c1];

    // ---- chunk loop: 13 M-tiles of 16 rows, in chunks of (4,4,4,1) tiles ----
    for (int ch = 0; ch < 4; ++ch) {
        const int row0 = ch * 64;
        const int ntl  = (ch < 3) ? 4 : 1;
        const int rows = ntl * 16;

        // stage features -> bf16 LDS [row][k] (pad rows = 0)
        for (int idx = tid; idx < rows * 16; idx += NTHREADS) {
            const int r = idx >> 4, c4 = idx & 15;
            const int l = row0 + r;
            float4 v = make_float4(0.f, 0.f, 0.f, 0.f);
            if (l < LL) v = ((const float4*)features)[((size_t)b * LL + l) * 16 + c4];
            ushort4 o; o.x = f2bf(v.x); o.y = f2bf(v.y); o.z = f2bf(v.z); o.w = f2bf(v.w);
            *(ushort4*)&s_feat[r * PITCH_F + c4 * 4] = o;
        }
        // stage gathered item rows -> bf16 LDS x3[row][0..127]
        for (int idx = tid; idx < rows * 32; idx += NTHREADS) {
            const int r = idx >> 5, c4 = idx & 31;
            const int l = row0 + r;
            float4 v = make_float4(0.f, 0.f, 0.f, 0.f);
            if (l < LL) {
                const int id = item_ids[(size_t)b * LL + l];
                v = ((const float4*)item_emb)[(size_t)id * 32 + c4];
            }
            ushort4 o; o.x = f2bf(v.x); o.y = f2bf(v.y); o.z = f2bf(v.z); o.w = f2bf(v.w);
            *(ushort4*)&s_x3[r * PITCH_X3 + c4 * 4] = o;
        }
        __syncthreads();

        // ---- layer 1: fx = relu(feat @ W1f^T + bias1), K=64 ----
        {
            const unsigned short* p = wsw + WS_W1;
            asm volatile("" : "+s"(p));   // block LICM hoist of B loads
            shortx8 B[2][2];
            #pragma unroll
            for (int nt = 0; nt < 2; ++nt)
                #pragma unroll
                for (int ks = 0; ks < 2; ++ks)
                    B[nt][ks] = *(const shortx8*)(p + (nw * 32 + nt * 16 + m) * 64 + ks * 32 + q * 8);
            #pragma unroll
            for (int t = 0; t < 2; ++t) {
                const int mt = mw * 2 + t;
                if (mt < ntl) {
                    floatx4 a0 = {0.f,0.f,0.f,0.f}, a1 = {0.f,0.f,0.f,0.f};
                    const unsigned short* ap = s_feat + (mt * 16 + m) * PITCH_F + q * 8;
                    #pragma unroll
                    for (int ks = 0; ks < 2; ++ks) {
                        shortx8 af = *(const shortx8*)(ap + ks * 32);
                        a0 = MFMA16(af, B[0][ks], a0);
                        a1 = MFMA16(af, B[1][ks], a1);
                    }
                    #pragma unroll
                    for (int r = 0; r < 4; ++r) {
                        const int row = mt * 16 + q * 4 + r;
                        float v0 = fmaxf(a0[r] + bias1_0, 0.f);
                        float v1 = fmaxf(a1[r] + bias1_1, 0.f);
                        s_fx[row * PITCH_FX + c0] = f2bf(v0);
                        s_fx[row * PITCH_FX + c1] = f2bf(v1);
                    }
                }
            }
        }
        __syncthreads();

        // ---- layer 2: comp = relu(fx @ W2^T + bias2) -> x3 cols 128..255, K=128 ----
        {
            const unsigned short* p = wsw + WS_W2;
            asm volatile("" : "+s"(p));
            shortx8 B[2][4];
            #pragma unroll
            for (int nt = 0; nt < 2; ++nt)
                #pragma unroll
                for (int ks = 0; ks < 4; ++ks)
                    B[nt][ks] = *(const shortx8*)(p + (nw * 32 + nt * 16 + m) * 128 + ks * 32 + q * 8);
            #pragma unroll
            for (int t = 0; t < 2; ++t) {
                const int mt = mw * 2 + t;
                if (mt < ntl) {
                    floatx4 a0 = {0.f,0.f,0.f,0.f}, a1 = {0.f,0.f,0.f,0.f};
                    const unsigned short* ap = s_fx + (mt * 16 + m) * PITCH_FX + q * 8;
                    #pragma unroll
                    for (int ks = 0; ks < 4; ++ks) {
                        shortx8 af = *(const shortx8*)(ap + ks * 32);
                        a0 = MFMA16(af, B[0][ks], a0);
                        a1 = MFMA16(af, B[1][ks], a1);
                    }
                    #pragma unroll
                    for (int r = 0; r < 4; ++r) {
                        const int row = mt * 16 + q * 4 + r;
                        float v0 = fmaxf(a0[r] + bias2_0, 0.f);
                        float v1 = fmaxf(a1[r] + bias2_1, 0.f);
                        s_x3[row * PITCH_X3 + EE + c0] = f2bf(v0);
                        s_x3[row * PITCH_X3 + EE + c1] = f2bf(v1);
                    }
                }
            }
        }
        __syncthreads();

        // ---- layer 3: h = relu([items|comp] @ W3'^T + bias3); logits, K=256 ----
        {
            const unsigned short* p = wsw + WS_W3;
            asm volatile("" : "+s"(p));
            shortx8 B[2][8];
            #pragma unroll
            for (int nt = 0; nt < 2; ++nt)
                #pragma unroll
                for (int ks = 0; ks < 8; ++ks)
                    B[nt][ks] = *(const shortx8*)(p + (nw * 32 + nt * 16 + m) * 256 + ks * 32 + q * 8);
            #pragma unroll
            for (int t = 0; t < 2; ++t) {
                const int mt = mw * 2 + t;
                if (mt < ntl) {
                    floatx4 a0 = {0.f,0.f,0.f,0.f}, a1 = {0.f,0.f,0.f,0.f};
                    const unsigned short* ap = s_x3 + (mt * 16 + m) * PITCH_X3 + q * 8;
                    #pragma unroll
                    for (int ks = 0; ks < 8; ++ks) {
                        shortx8 af = *(const shortx8*)(ap + ks * 32);
                        a0 = MFMA16(af, B[0][ks], a0);
                        a1 = MFMA16(af, B[1][ks], a1);
                    }
                    #pragma unroll
                    for (int r = 0; r < 4; ++r) {
                        float v0 = fmaxf(a0[r] + bias3_0, 0.f);
                        float v1 = fmaxf(a1[r] + bias3_1, 0.f);
                        float pp = v0 * w2_0 + v1 * w2_1;
                        pp += __shfl_xor(pp, 1, 64);   // reduce over 16-lane n dim
                        pp += __shfl_xor(pp, 2, 64);
                        pp += __shfl_xor(pp, 4, 64);
                        pp += __shfl_xor(pp, 8, 64);
                        if (m == 0) s_lp[wv][row0 + mt * 16 + q * 4 + r] = pp;
                    }
                }
            }
        }
        __syncthreads();
    }

    // ---- softmax over L=200 ----
    const int wid = tid >> 6;
    float lv = -INFINITY;
    if (tid < LL) {
        lv = b2[0];
        #pragma unroll
        for (int w = 0; w < 8; ++w) lv += s_lp[w][tid];
    }
    {
        float mx = waveMax(lv);
        if ((tid & 63) == 0) s_red[wid] = mx;
        __syncthreads();
        if (tid == 0) {
            float g = s_red[0];
            #pragma unroll
            for (int w = 1; w < 8; ++w) g = fmaxf(g, s_red[w]);
            s_red[8] = g;
        }
        __syncthreads();
    }
    const float gmax = s_red[8];
    __syncthreads();
    float ex = (tid < LL) ? __expf(lv - gmax) : 0.f;
    {
        float s = waveSum(ex);
        if ((tid & 63) == 0) s_red[wid] = s;
        __syncthreads();
        if (tid == 0) {
            float g = 0.f;
            #pragma unroll
            for (int w = 0; w < 8; ++w) g += s_red[w];
            s_red[8] = g;
        }
        __syncthreads();
    }
    const float inv = 1.f / s_red[8];
    if (tid < LL) s_attn[tid] = ex * inv;
    __syncthreads();

    // ---- out[b] = user + sum_l attn[l] * item_emb[item_ids[b,l]]  (fp32) ----
    {
        const int e = tid & (EE - 1);
        const int g = tid >> 7;            // 0..3, each covers 50 l's
        float acc = 0.f;
        const int lstart = g * (LL / 4);
        for (int l = lstart; l < lstart + LL / 4; ++l) {
            const float a  = s_attn[l];
            const int  id  = item_ids[(size_t)b * LL + l];
            acc += a * item_emb[(size_t)id * EE + e];
        }
        s_part[g][e] = acc;
        __syncthreads();
        if (tid < EE)
            out[(size_t)b * EE + tid] = s_user[tid] + s_part[0][tid] + s_part[1][tid]
                                      + s_part[2][tid] + s_part[3][tid];
    }
}

extern "C" void kernel_launch(void* const* d_in, const int* in_sizes, int n_in,
                              void* d_out, int out_size, void* d_ws, size_t ws_size,
                              hipStream_t stream) {
    const int*   user_ids = (const int*)  d_in[0];
    const int*   item_ids = (const int*)  d_in[1];
    const float* features = (const float*)d_in[2];
    const float* user_emb = (const float*)d_in[3];
    const float* item_emb = (const float*)d_in[4];
    const float* feat_w1  = (const float*)d_in[5];
    const float* feat_b1  = (const float*)d_in[6];
    const float* feat_w2  = (const float*)d_in[7];
    const float* feat_b2  = (const float*)d_in[8];
    const float* w1       = (const float*)d_in[9];
    const float* b1       = (const float*)d_in[10];
    const float* w2       = (const float*)d_in[11];
    const float* b2       = (const float*)d_in[12];
    float* out = (float*)d_out;
    unsigned short* wsw = (unsigned short*)d_ws;

    prep_weights<<<(WS_TOTAL + 255) / 256, 256, 0, stream>>>(feat_w1, feat_w2, w1, wsw);
    usernet_mfma<<<BB, NTHREADS, 0, stream>>>(user_ids, item_ids, features,
                                              user_emb, item_emb,
                                              feat_w1, feat_b1, feat_b2,
                                              w1, b1, w2, b2, wsw, out);
}

// Round 6
// 773.238 us; speedup vs baseline: 1.2741x; 1.2003x over previous
//
#include <hip/hip_runtime.h>
#include <math.h>

#define BB 4096
#define LL 200
#define EE 128
#define FF 64
#define NTHREADS 512   // 8 waves: 0-3 -> b0, 4-7 -> b1; each wave owns whole M-tiles

// Padded LDS pitches (bf16 elems). pitch_bytes = 16*odd -> ds_read_b128
// 16B-column = (m + 4ks + q) mod 8, uniform -> conflict-free.
#define PB1 72     // B1 table [n=128][k=64]
#define PB2 136    // B2 table [n=128][k=128]
#define PB3 264    // B3 table [n=128][k=256]
#define PSC 136    // per-wave scratch [row=16][k=128]

// bf16 weight table in d_ws (unpadded), prepped once per launch:
#define WS_W1 0
#define WS_W2 8192
#define WS_W3 24576
#define WS_TOTAL 57344

typedef __attribute__((ext_vector_type(4))) float  floatx4;
typedef __attribute__((ext_vector_type(8))) short  shortx8;

#define MFMA16(a, b, c) __builtin_amdgcn_mfma_f32_16x16x32_bf16((a), (b), (c), 0, 0, 0)

__device__ __forceinline__ unsigned short f2bf(float f) {
    union { float f; unsigned u; } c; c.f = f;
    return (unsigned short)((c.u + 0x7fffu + ((c.u >> 16) & 1u)) >> 16);
}

__device__ __forceinline__ shortx8 cvt8(float4 a, float4 b) {
    shortx8 r;
    r[0] = (short)f2bf(a.x); r[1] = (short)f2bf(a.y);
    r[2] = (short)f2bf(a.z); r[3] = (short)f2bf(a.w);
    r[4] = (short)f2bf(b.x); r[5] = (short)f2bf(b.y);
    r[6] = (short)f2bf(b.z); r[7] = (short)f2bf(b.w);
    return r;
}

__device__ __forceinline__ float waveMax(float v) {
    #pragma unroll
    for (int off = 32; off > 0; off >>= 1)
        v = fmaxf(v, __shfl_xor(v, off, 64));
    return v;
}
__device__ __forceinline__ float waveSum(float v) {
    #pragma unroll
    for (int off = 32; off > 0; off >>= 1)
        v += __shfl_xor(v, off, 64);
    return v;
}

// One-time per launch: fp32 -> bf16 weight repack (unpadded [n][k] rows).
__global__ __launch_bounds__(256)
void prep_weights(const float* __restrict__ feat_w1,
                  const float* __restrict__ feat_w2,
                  const float* __restrict__ w1,
                  unsigned short* __restrict__ wsw)
{
    int i = blockIdx.x * 256 + threadIdx.x;
    if (i >= WS_TOTAL) return;
    float v;
    if (i < WS_W2) {                       // feat_w1 feature cols [n][k=64]
        int n = i >> 6, k = i & 63;
        v = feat_w1[n * (EE + FF) + EE + k];
    } else if (i < WS_W3) {                // feat_w2 [n][k=128]
        int j = i - WS_W2;
        int n = j >> 7, k = j & 127;
        v = feat_w2[n * EE + k];
    } else {                               // w1 item|comp cols [n][k=256]
        int j = i - WS_W3;
        int n = j >> 8, k = j & 255;
        v = w1[n * (3 * EE) + EE + k];
    }
    wsw[i] = f2bf(v);
}

// R2-R5 lesson: barrier-phased structure caps MfmaUtil at ~7% (tiny work per
// barrier, 17 barriers/block) and the allocator never grants >64 VGPRs for
// persistent fragments. New structure: waves own M-tiles end-to-end, weights
// in LDS (1 ds_read_b128 per B-frag, conflict-free padded pitch), fx->comp
// transposed through per-wave LDS scratch. Main loop has ZERO barriers.
__global__ __attribute__((amdgpu_flat_work_group_size(NTHREADS, NTHREADS),
                          amdgpu_waves_per_eu(1, 2)))
void usernet_wavetile(const int* __restrict__ user_ids,
                      const int* __restrict__ item_ids,
                      const float* __restrict__ features,
                      const float* __restrict__ user_emb,
                      const float* __restrict__ item_emb,
                      const float* __restrict__ feat_w1,
                      const float* __restrict__ feat_b1,
                      const float* __restrict__ feat_b2,
                      const float* __restrict__ w1,
                      const float* __restrict__ b1,
                      const float* __restrict__ w2,
                      const unsigned short* __restrict__ wsw,
                      float* __restrict__ out)
{
    __shared__ __align__(16) unsigned short sB1[128 * PB1];      // 18432 B
    __shared__ __align__(16) unsigned short sB2[128 * PB2];      // 34816 B
    __shared__ __align__(16) unsigned short sB3[128 * PB3];      // 67584 B
    __shared__ __align__(16) unsigned short sscr[8][16 * PSC];   // 34816 B
    __shared__ float s_user[2][EE];
    __shared__ float s_b1f[2][EE];     // W1a@user + feat_b1, per b
    __shared__ float s_b3f[2][EE];     // W3a@user + b1, per b
    __shared__ float s_b2f[EE];
    __shared__ float s_w2f[EE];
    __shared__ float s_logits[2][208]; // logits, then attn in place
    __shared__ float s_red[2][8];
    // total 161472 B <= 163840

    const int tid  = threadIdx.x;
    const int lane = tid & 63;
    const int wv   = tid >> 6;         // 0..7
    const int m    = lane & 15;
    const int q    = lane >> 4;
    const int bsel = wv >> 2;          // which batch row this wave serves
    const int wloc = wv & 3;           // wave index within the b-group
    const long long bb = 2LL * blockIdx.x + bsel;

    // ---- stage weights into padded LDS (14 x int4 per thread) ----
    for (int i = tid; i < WS_TOTAL / 8; i += NTHREADS) {
        const int e0 = i << 3;
        int4 v = ((const int4*)wsw)[i];
        unsigned short* dst;
        if (e0 < WS_W2)      { int n = e0 >> 6,  k = e0 & 63;
                               dst = &sB1[n * PB1 + k]; }
        else if (e0 < WS_W3) { int j = e0 - WS_W2; int n = j >> 7, k = j & 127;
                               dst = &sB2[n * PB2 + k]; }
        else                 { int j = e0 - WS_W3; int n = j >> 8, k = j & 255;
                               dst = &sB3[n * PB3 + k]; }
        *(int4*)dst = v;
    }
    // users + small vectors
    if (tid < 64) {
        const int ub = tid >> 5, ui = tid & 31;
        const int uid = user_ids[2 * blockIdx.x + ub];
        ((float4*)s_user[ub])[ui] = ((const float4*)(user_emb + (size_t)uid * EE))[ui];
    }
    if (tid >= 64 && tid < 64 + EE) {
        s_b2f[tid - 64] = feat_b2[tid - 64];
        s_w2f[tid - 64] = w2[tid - 64];
    }
    __syncthreads();

    // ---- fp32 user folds (once per block, 512 threads = 2b x 2mat x 128) ----
    {
        const int fb = tid >> 8, fh = (tid >> 7) & 1, fe = tid & 127;
        const float* wrow = fh ? (w1 + (size_t)fe * (3 * EE))
                               : (feat_w1 + (size_t)fe * (EE + FF));
        float a = 0.f;
        #pragma unroll 8
        for (int k = 0; k < EE; ++k) a += wrow[k] * s_user[fb][k];
        if (fh == 0) s_b1f[fb][fe] = a + feat_b1[fe];
        else         s_b3f[fb][fe] = a + b1[fe];
    }
    __syncthreads();

    // ---- per-wave per-lane bias registers (col = nt*16 + m) ----
    float b1r[8], b2r[8], b3r[8], w2r[8];
    #pragma unroll
    for (int nt = 0; nt < 8; ++nt) {
        const int c = nt * 16 + m;
        b1r[nt] = s_b1f[bsel][c];
        b2r[nt] = s_b2f[c];
        b3r[nt] = s_b3f[bsel][c];
        w2r[nt] = s_w2f[c];
    }

    // ================= barrier-free main loop =================
    for (int t = wloc; t < 13; t += 4) {
        const int  l0   = t * 16;
        const int  lrow = l0 + m;
        const bool rv   = lrow < LL;
        const float4 z  = make_float4(0.f, 0.f, 0.f, 0.f);

        // ---- A frags: features fp32 -> bf16, K=64 ----
        shortx8 af0, af1;
        {
            const float4* fp = (const float4*)(features +
                               ((size_t)bb * LL + (rv ? lrow : 0)) * FF);
            float4 a0 = rv ? fp[q * 2]     : z;
            float4 a1 = rv ? fp[q * 2 + 1] : z;
            float4 a2 = rv ? fp[8 + q * 2]     : z;
            float4 a3 = rv ? fp[8 + q * 2 + 1] : z;
            af0 = cvt8(a0, a1); af1 = cvt8(a2, a3);
        }
        // ---- layer 1: fx = relu(feat @ W1f^T + b1f) -> scratch (A-layout) ----
        #pragma unroll
        for (int nt = 0; nt < 8; ++nt) {
            const int wr = (nt * 16 + m) * PB1 + q * 8;
            floatx4 c = {0.f, 0.f, 0.f, 0.f};
            c = MFMA16(af0, *(const shortx8*)&sB1[wr], c);
            c = MFMA16(af1, *(const shortx8*)&sB1[wr + 32], c);
            #pragma unroll
            for (int r = 0; r < 4; ++r) {
                float v = fmaxf(c[r] + b1r[nt], 0.f);
                sscr[wv][(q * 4 + r) * PSC + nt * 16 + m] = f2bf(v);
            }
        }
        // ---- layer 2: comp = relu(fx @ W2^T + b2f) -> scratch (overwrite) ----
        shortx8 ax0, ax1, ax2, ax3;
        {
            const unsigned short* sp = &sscr[wv][m * PSC + q * 8];
            ax0 = *(const shortx8*)(sp);
            ax1 = *(const shortx8*)(sp + 32);
            ax2 = *(const shortx8*)(sp + 64);
            ax3 = *(const shortx8*)(sp + 96);
        }
        #pragma unroll
        for (int nt = 0; nt < 8; ++nt) {
            const int wr = (nt * 16 + m) * PB2 + q * 8;
            floatx4 c = {0.f, 0.f, 0.f, 0.f};
            c = MFMA16(ax0, *(const shortx8*)&sB2[wr], c);
            c = MFMA16(ax1, *(const shortx8*)&sB2[wr + 32], c);
            c = MFMA16(ax2, *(const shortx8*)&sB2[wr + 64], c);
            c = MFMA16(ax3, *(const shortx8*)&sB2[wr + 96], c);
            #pragma unroll
            for (int r = 0; r < 4; ++r) {
                float v = fmaxf(c[r] + b2r[nt], 0.f);
                sscr[wv][(q * 4 + r) * PSC + nt * 16 + m] = f2bf(v);
            }
        }
        // ---- layer 3: h = relu([items|comp] @ W3'^T + b3f); logits ----
        shortx8 ai0, ai1, ai2, ai3, ac0, ac1, ac2, ac3;
        {
            const int id = rv ? item_ids[(size_t)bb * LL + lrow] : 0;
            const float4* ip = (const float4*)(item_emb + (size_t)id * EE);
            float4 t0, t1;
            t0 = rv ? ip[q * 2]          : z; t1 = rv ? ip[q * 2 + 1]      : z; ai0 = cvt8(t0, t1);
            t0 = rv ? ip[8 + q * 2]      : z; t1 = rv ? ip[8 + q * 2 + 1]  : z; ai1 = cvt8(t0, t1);
            t0 = rv ? ip[16 + q * 2]     : z; t1 = rv ? ip[16 + q * 2 + 1] : z; ai2 = cvt8(t0, t1);
            t0 = rv ? ip[24 + q * 2]     : z; t1 = rv ? ip[24 + q * 2 + 1] : z; ai3 = cvt8(t0, t1);
            const unsigned short* sp = &sscr[wv][m * PSC + q * 8];
            ac0 = *(const shortx8*)(sp);
            ac1 = *(const shortx8*)(sp + 32);
            ac2 = *(const shortx8*)(sp + 64);
            ac3 = *(const shortx8*)(sp + 96);
        }
        floatx4 pp = {0.f, 0.f, 0.f, 0.f};
        #pragma unroll
        for (int nt = 0; nt < 8; ++nt) {
            const int wr = (nt * 16 + m) * PB3 + q * 8;
            floatx4 c = {0.f, 0.f, 0.f, 0.f};
            c = MFMA16(ai0, *(const shortx8*)&sB3[wr], c);
            c = MFMA16(ai1, *(const shortx8*)&sB3[wr + 32], c);
            c = MFMA16(ai2, *(const shortx8*)&sB3[wr + 64], c);
            c = MFMA16(ai3, *(const shortx8*)&sB3[wr + 96], c);
            c = MFMA16(ac0, *(const shortx8*)&sB3[wr + 128], c);
            c = MFMA16(ac1, *(const shortx8*)&sB3[wr + 160], c);
            c = MFMA16(ac2, *(const shortx8*)&sB3[wr + 192], c);
            c = MFMA16(ac3, *(const shortx8*)&sB3[wr + 224], c);
            #pragma unroll
            for (int r = 0; r < 4; ++r) {
                float v = fmaxf(c[r] + b3r[nt], 0.f);
                pp[r] += v * w2r[nt];
            }
        }
        #pragma unroll
        for (int r = 0; r < 4; ++r) {
            float p = pp[r];
            p += __shfl_xor(p, 1, 64);   // reduce over the 16-lane n dim
            p += __shfl_xor(p, 2, 64);
            p += __shfl_xor(p, 4, 64);
            p += __shfl_xor(p, 8, 64);
            if (m == 0) s_logits[bsel][l0 + q * 4 + r] = p;
        }
    }
    __syncthreads();

    // ---- softmax over L=200, two independent halves (b2 scalar cancels) ----
    const int sb = tid >> 8;
    const int st = tid & 255;
    const int sw = st >> 6;
    float lv = (st < LL) ? s_logits[sb][st] : -INFINITY;
    {
        float mx = waveMax(lv);
        if ((st & 63) == 0) s_red[sb][sw] = mx;
    }
    __syncthreads();
    const float gmax = fmaxf(fmaxf(s_red[sb][0], s_red[sb][1]),
                             fmaxf(s_red[sb][2], s_red[sb][3]));
    float ex = (st < LL) ? __expf(lv - gmax) : 0.f;
    {
        float sm = waveSum(ex);
        if ((st & 63) == 0) s_red[sb][4 + sw] = sm;
    }
    __syncthreads();
    const float tot = s_red[sb][4] + s_red[sb][5] + s_red[sb][6] + s_red[sb][7];
    if (st < LL) s_logits[sb][st] = ex / tot;
    __syncthreads();

    // ---- out[b] = user + sum_l attn[l] * item_emb[item_ids[b,l]] (fp32) ----
    {
        const int eb = tid >> 8;           // b within pair
        const int eg = (tid >> 7) & 1;     // l-half
        const int ee = tid & 127;
        const long long gb = 2LL * blockIdx.x + eb;
        float acc = 0.f;
        for (int l = eg * 100; l < eg * 100 + 100; ++l) {
            const float a = s_logits[eb][l];
            const int  id = item_ids[(size_t)gb * LL + l];
            acc += a * item_emb[(size_t)id * EE + ee];
        }
        float* part = (float*)sscr;        // reuse scratch for partials
        part[(eb * 2 + eg) * EE + ee] = acc;
        __syncthreads();
        if (tid < 2 * EE) {
            const int ob = tid >> 7, oe = tid & 127;
            out[((size_t)(2 * blockIdx.x + ob)) * EE + oe] =
                s_user[ob][oe] + part[(ob * 2) * EE + oe] + part[(ob * 2 + 1) * EE + oe];
        }
    }
}

extern "C" void kernel_launch(void* const* d_in, const int* in_sizes, int n_in,
                              void* d_out, int out_size, void* d_ws, size_t ws_size,
                              hipStream_t stream) {
    const int*   user_ids = (const int*)  d_in[0];
    const int*   item_ids = (const int*)  d_in[1];
    const float* features = (const float*)d_in[2];
    const float* user_emb = (const float*)d_in[3];
    const float* item_emb = (const float*)d_in[4];
    const float* feat_w1  = (const float*)d_in[5];
    const float* feat_b1  = (const float*)d_in[6];
    const float* feat_w2  = (const float*)d_in[7];
    const float* feat_b2  = (const float*)d_in[8];
    const float* w1       = (const float*)d_in[9];
    const float* b1       = (const float*)d_in[10];
    const float* w2       = (const float*)d_in[11];
    float* out = (float*)d_out;
    unsigned short* wsw = (unsigned short*)d_ws;

    prep_weights<<<(WS_TOTAL + 255) / 256, 256, 0, stream>>>(feat_w1, feat_w2, w1, wsw);
    usernet_wavetile<<<BB / 2, NTHREADS, 0, stream>>>(user_ids, item_ids, features,
                                                      user_emb, item_emb,
                                                      feat_w1, feat_b1, feat_b2,
                                                      w1, b1, w2, wsw, out);
}